// Round 17
// baseline (31.105 us; speedup 1.0000x reference)
//
#include <hip/hip_runtime.h>

// SSIM map: refl-pad(1) + 3x3 avg-pool stencil, B=16 C=3 H=512 W=512 fp32.
// Ledger: R11 rcp+fma 32.1 | R15 ROWS32+XCD 29.4 BEST (fabric model MATCHED:
// bytes 162->155MB, dur -8%; occupancy fell and didn't matter).
// Model: ~5.3 TB/s L2/L3-fabric ceiling for this pattern; compulsory 151MB
// -> ~28.1us floor. R16/R17: last point on byte-vs-waves curve — ROWS=64
// (halo 66/64, -2% bytes) at 768 blocks = 3/CU. Confirms or bounds the
// model; R15 is the fallback if wave-count dominates.

#define HH 512
#define WW 512
#define ROWS 64          // rows per thread; halo factor 66/64
#define SSIM_C1 1e-4f    // 0.01^2
#define SSIM_C2 9e-4f    // 0.03^2

__global__ __launch_bounds__(256) void ssim_kernel(const float* __restrict__ x,
                                                   const float* __restrict__ y,
                                                   float* __restrict__ out) {
    // XCD-aware remap: 768 blocks, 768%8==0, cpx=96 => XCD k owns 6 whole
    // planes; vertical halo re-reads hit the local L2.
    const int orig    = blockIdx.x + 2 * (blockIdx.y + 8 * blockIdx.z);
    const int logical = (orig & 7) * 96 + (orig >> 3);
    const int bz  = logical >> 4;         // plane 0..47
    const int rem = logical & 15;
    const int by  = rem >> 1;             // strip 0..7
    const int bx  = rem & 1;              // col-half 0..1

    const int col   = bx * 256 + threadIdx.x;   // 0..511
    const int row0  = by * ROWS;
    const size_t po = (size_t)bz * (size_t)(HH * WW);
    const float* xp = x + po;
    const float* yp = y + po;
    float* op       = out + po;

    // reflection-pad(1) column neighbors
    const int cl = (col == 0)      ? 1      : col - 1;
    const int cr = (col == WW - 1) ? WW - 2 : col + 1;

    // 3-deep sliding window of horizontal row-sums for 5 quantities.
    float sx0, sy0, sxx0, syy0, sxy0;
    float sx1, sy1, sxx1, syy1, sxy1;

#define LOADROW(r, SX, SY, SXX, SYY, SXY) do {                      \
    int rr_ = (r) < 0 ? 1 : ((r) >= HH ? HH - 2 : (r));             \
    const float* xr_ = xp + rr_ * WW;                               \
    const float* yr_ = yp + rr_ * WW;                               \
    float xl_ = xr_[cl], xc_ = xr_[col], xv_ = xr_[cr];             \
    float yl_ = yr_[cl], yc_ = yr_[col], yv_ = yr_[cr];             \
    SX  = xl_ + xc_ + xv_;                                          \
    SY  = yl_ + yc_ + yv_;                                          \
    SXX = fmaf(xl_, xl_, fmaf(xc_, xc_, xv_ * xv_));                \
    SYY = fmaf(yl_, yl_, fmaf(yc_, yc_, yv_ * yv_));                \
    SXY = fmaf(xl_, yl_, fmaf(xc_, yc_, xv_ * yv_));                \
} while (0)

    // Prime rows row0-1 (reflected) and row0.
    LOADROW(row0 - 1, sx0, sy0, sxx0, syy0, sxy0);
    LOADROW(row0,     sx1, sy1, sxx1, syy1, sxy1);

    const float inv9 = 1.0f / 9.0f;

    #pragma unroll 4
    for (int i = 0; i < ROWS; ++i) {
        const int r = row0 + i;
        float sx2, sy2, sxx2, syy2, sxy2;
        LOADROW(r + 1, sx2, sy2, sxx2, syy2, sxy2);

        const float sx  = sx0  + sx1  + sx2;
        const float sy  = sy0  + sy1  + sy2;
        const float sxx = sxx0 + sxx1 + sxx2;
        const float syy = syy0 + syy1 + syy2;
        const float sxy = sxy0 + sxy1 + sxy2;

        const float mux   = sx * inv9;
        const float muy   = sy * inv9;
        const float sigx  = fmaf(-mux, mux, sxx * inv9);
        const float sigy  = fmaf(-muy, muy, syy * inv9);
        const float sigxy = fmaf(-mux, muy, sxy * inv9);

        const float n = fmaf(mux + mux, muy, SSIM_C1) *
                        fmaf(2.0f, sigxy, SSIM_C2);
        const float d = fmaf(mux, mux, fmaf(muy, muy, SSIM_C1)) *
                        (sigx + sigy + SSIM_C2);

        // fast reciprocal: v_rcp_f32 (~1 ulp) instead of IEEE div
        const float rd = __builtin_amdgcn_rcpf(d + 1e-8f);
        float v = fmaf(n * rd, -0.5f, 0.5f);
        v = fminf(fmaxf(v, 0.0f), 1.0f);

        op[(size_t)r * WW + col] = v;

        sx0 = sx1;  sy0 = sy1;  sxx0 = sxx1;  syy0 = syy1;  sxy0 = sxy1;
        sx1 = sx2;  sy1 = sy2;  sxx1 = sxx2;  syy1 = syy2;  sxy1 = sxy2;
    }
#undef LOADROW
}

extern "C" void kernel_launch(void* const* d_in, const int* in_sizes, int n_in,
                              void* d_out, int out_size, void* d_ws, size_t ws_size,
                              hipStream_t stream) {
    const float* x = (const float*)d_in[0];
    const float* y = (const float*)d_in[1];
    float* out     = (float*)d_out;

    // B*C = 48 planes of 512x512; 768 blocks = 3/CU
    dim3 block(256, 1, 1);
    dim3 grid(WW / 256, HH / ROWS, 48);   // (2, 8, 48)
    ssim_kernel<<<grid, block, 0, stream>>>(x, y, out);
}

// Round 18
// 29.330 us; speedup vs baseline: 1.0605x; 1.0605x over previous
//
#include <hip/hip_runtime.h>

// SSIM map: refl-pad(1) + 3x3 avg-pool stencil, B=16 C=3 H=512 W=512 fp32.
// FINAL (R15 restored): byte-vs-waves curve complete & convex:
// ROWS 8/16/32/64 -> 33.6/32.1/29.4/31.1 us. Minimum at ROWS=32 (6 blk/CU).
// Model (12 experiments): mixed R+W stencil sustains ~5.3 TB/s L2/L3
// fabric; compulsory 151MB -> ~28.2us floor; this kernel = 29.4us (~4%).
// Wins: rcp+fma (R11, -1.5us), ROWS32+XCD-swizzle (R15, -2.7us).
// Falsified: f4 vectorize, NT store, sw+asm pipelining, shfl halo,
// dual-plane ILP, occupancy up/down.

#define HH 512
#define WW 512
#define ROWS 32          // rows per thread; halo factor 34/32 — curve minimum
#define SSIM_C1 1e-4f    // 0.01^2
#define SSIM_C2 9e-4f    // 0.03^2

__global__ __launch_bounds__(256) void ssim_kernel(const float* __restrict__ x,
                                                   const float* __restrict__ y,
                                                   float* __restrict__ out) {
    // XCD-aware remap: 1536 blocks, 1536%8==0, cpx=192 => XCD k owns 6
    // whole planes; vertical halo re-reads hit the local L2.
    const int orig    = blockIdx.x + 2 * (blockIdx.y + 16 * blockIdx.z);
    const int logical = (orig & 7) * 192 + (orig >> 3);
    const int bz  = logical >> 5;         // plane 0..47
    const int rem = logical & 31;
    const int by  = rem >> 1;             // strip 0..15
    const int bx  = rem & 1;              // col-half 0..1

    const int col   = bx * 256 + threadIdx.x;   // 0..511
    const int row0  = by * ROWS;
    const size_t po = (size_t)bz * (size_t)(HH * WW);
    const float* xp = x + po;
    const float* yp = y + po;
    float* op       = out + po;

    // reflection-pad(1) column neighbors
    const int cl = (col == 0)      ? 1      : col - 1;
    const int cr = (col == WW - 1) ? WW - 2 : col + 1;

    // 3-deep sliding window of horizontal row-sums for 5 quantities.
    float sx0, sy0, sxx0, syy0, sxy0;
    float sx1, sy1, sxx1, syy1, sxy1;

#define LOADROW(r, SX, SY, SXX, SYY, SXY) do {                      \
    int rr_ = (r) < 0 ? 1 : ((r) >= HH ? HH - 2 : (r));             \
    const float* xr_ = xp + rr_ * WW;                               \
    const float* yr_ = yp + rr_ * WW;                               \
    float xl_ = xr_[cl], xc_ = xr_[col], xv_ = xr_[cr];             \
    float yl_ = yr_[cl], yc_ = yr_[col], yv_ = yr_[cr];             \
    SX  = xl_ + xc_ + xv_;                                          \
    SY  = yl_ + yc_ + yv_;                                          \
    SXX = fmaf(xl_, xl_, fmaf(xc_, xc_, xv_ * xv_));                \
    SYY = fmaf(yl_, yl_, fmaf(yc_, yc_, yv_ * yv_));                \
    SXY = fmaf(xl_, yl_, fmaf(xc_, yc_, xv_ * yv_));                \
} while (0)

    // Prime rows row0-1 (reflected) and row0.
    LOADROW(row0 - 1, sx0, sy0, sxx0, syy0, sxy0);
    LOADROW(row0,     sx1, sy1, sxx1, syy1, sxy1);

    const float inv9 = 1.0f / 9.0f;

    #pragma unroll 4
    for (int i = 0; i < ROWS; ++i) {
        const int r = row0 + i;
        float sx2, sy2, sxx2, syy2, sxy2;
        LOADROW(r + 1, sx2, sy2, sxx2, syy2, sxy2);

        const float sx  = sx0  + sx1  + sx2;
        const float sy  = sy0  + sy1  + sy2;
        const float sxx = sxx0 + sxx1 + sxx2;
        const float syy = syy0 + syy1 + syy2;
        const float sxy = sxy0 + sxy1 + sxy2;

        const float mux   = sx * inv9;
        const float muy   = sy * inv9;
        const float sigx  = fmaf(-mux, mux, sxx * inv9);
        const float sigy  = fmaf(-muy, muy, syy * inv9);
        const float sigxy = fmaf(-mux, muy, sxy * inv9);

        const float n = fmaf(mux + mux, muy, SSIM_C1) *
                        fmaf(2.0f, sigxy, SSIM_C2);
        const float d = fmaf(mux, mux, fmaf(muy, muy, SSIM_C1)) *
                        (sigx + sigy + SSIM_C2);

        // fast reciprocal: v_rcp_f32 (~1 ulp) instead of IEEE div
        const float rd = __builtin_amdgcn_rcpf(d + 1e-8f);
        float v = fmaf(n * rd, -0.5f, 0.5f);
        v = fminf(fmaxf(v, 0.0f), 1.0f);

        op[(size_t)r * WW + col] = v;

        sx0 = sx1;  sy0 = sy1;  sxx0 = sxx1;  syy0 = syy1;  sxy0 = sxy1;
        sx1 = sx2;  sy1 = sy2;  sxx1 = sxx2;  syy1 = syy2;  sxy1 = sxy2;
    }
#undef LOADROW
}

extern "C" void kernel_launch(void* const* d_in, const int* in_sizes, int n_in,
                              void* d_out, int out_size, void* d_ws, size_t ws_size,
                              hipStream_t stream) {
    const float* x = (const float*)d_in[0];
    const float* y = (const float*)d_in[1];
    float* out     = (float*)d_out;

    // B*C = 48 planes of 512x512; 1536 blocks = 6/CU, one residency round
    dim3 block(256, 1, 1);
    dim3 grid(WW / 256, HH / ROWS, 48);   // (2, 16, 48)
    ssim_kernel<<<grid, block, 0, stream>>>(x, y, out);
}